// Round 7
// baseline (139.810 us; speedup 1.0000x reference)
//
#include <hip/hip_runtime.h>
#include <stdint.h>

typedef __bf16 bf16;
typedef bf16 bf16x8 __attribute__((ext_vector_type(8)));
typedef float floatx4 __attribute__((ext_vector_type(4)));

#define INV_T     2.0f                      // 1 / TEMPERATURE
#define SQRT_K    1.6986436206f             // sqrt(INV_T * log2(e))
#define INV_K     0.34657359028f            // ln(2)/2 = 1/(INV_T*log2(e))
#define GLOBAL_AS __attribute__((address_space(1)))
#define LDS_AS    __attribute__((address_space(3)))

// rep2 layout (16B chunks): chunk(r, ch) = (r>>6)*1024 + ch*64 + (r&63),
// ch = k>>3. MFMA A/B fragment loads and tile staging are fully coalesced,
// LDS fragment reads structurally conflict-free.

// ---------------------------------------------------------------------------
// Kernel 1: L2-normalize rows, scale by SQRT_K, write bf16 rep2 (swizzled).
// ---------------------------------------------------------------------------
__global__ __launch_bounds__(256) void nrm_kernel(const float* __restrict__ p1,
                                                  const float* __restrict__ p2,
                                                  uint32_t* __restrict__ rep2,
                                                  float* __restrict__ out) {
    int gt   = blockIdx.x * 256 + threadIdx.x;
    int row  = gt >> 6;
    int lane = gt & 63;
    const float* srcRow = (row < 4096) ? (p1 + (size_t)row * 128)
                                       : (p2 + (size_t)(row - 4096) * 128);
    float2 v = ((const float2*)srcRow)[lane];
    float ss = v.x * v.x + v.y * v.y;
#pragma unroll
    for (int s = 1; s < 64; s <<= 1) ss += __shfl_xor(ss, s, 64);
    float inv = SQRT_K / fmaxf(sqrtf(ss), 1e-12f);
    union { bf16 h[2]; uint32_t u; } pk;
    pk.h[0] = (bf16)(v.x * inv);
    pk.h[1] = (bf16)(v.y * inv);
    int chunk = (row >> 6) * 1024 + (lane >> 2) * 64 + (row & 63);
    rep2[chunk * 4 + (lane & 3)] = pk.u;
    if (gt == 0) *out = 0.0f;
}

// ---------------------------------------------------------------------------
// Kernel 2: SYMMETRIC rowsum partials + positive-pair dot.
// exp(sim) is symmetric -> compute only tiles (rb,cb) with cb >= rb (528 of
// 1024; lower-triangle blocks exit immediately). Each active block emits:
//   row partials (sum over its 256 cols)  -> rowsumP[row][cb]
//   col partials (sum over its 256 rows)  -> rowsumP[col][rb]   (cb != rb)
// Per-row slot coverage: {0..31} exactly once (cb>=b rowsums, rb<b colsums).
// Partner tiles (rb, rb+16) hold the (i, i+4096) pairs on their strip
// diagonals -> write pos[i] and pos[i+4096] from the same element.
// B staged via async global_load_lds, 2x16KB dbuf, 4 tiles, 1 barrier each.
// ---------------------------------------------------------------------------
__global__ __launch_bounds__(256, 4) void sim_kernel(const uint4* __restrict__ rep2,
                                                     float* __restrict__ rowsumP,
                                                     float* __restrict__ pos) {
    __shared__ uint4 lB[2][1024];       // 32 KB
    __shared__ float colPart[4][256];   // 4 KB cross-wave colsum combine

    const int cb = blockIdx.x;     // col block: cols [cb*256, +256)
    const int rb = blockIdx.y;     // row block: rows [rb*256, +256)
    if (cb < rb) return;           // symmetry: upper triangle only

    const int tid  = threadIdx.x;
    const int w    = tid >> 6;
    const int lane = tid & 63;
    const int quad = lane >> 4;
    const int lcol = lane & 15;

    const int wbase = rb * 256 + w * 64;       // wave's rows (64-aligned)
    const int pbase = (wbase + 4096) & 8191;   // partner 64-col window

    // A fragments: rows wbase+mi*16+lcol, k = ks*32+quad*8..+7
    bf16x8 aF[4][4];
    const uint4* aG = rep2 + (size_t)(wbase >> 6) * 1024;
#pragma unroll
    for (int mi = 0; mi < 4; mi++)
#pragma unroll
        for (int ks = 0; ks < 4; ks++)
            aF[mi][ks] = *(const bf16x8*)&aG[(ks * 4 + quad) * 64 + mi * 16 + lcol];

    float rs[16];
#pragma unroll
    for (int i = 0; i < 16; i++) rs[i] = 0.0f;

    // stage tile 0 (cols cb*256..+63)
    {
        const uint4* src = rep2 + (size_t)(cb * 4) * 1024;
#pragma unroll
        for (int j = 0; j < 4; j++)
            __builtin_amdgcn_global_load_lds(
                (const GLOBAL_AS uint32_t*)(src + j * 256 + tid),
                (LDS_AS uint32_t*)&lB[0][j * 256 + tid], 16, 0, 0);
    }
    __syncthreads();

    for (int t = 0; t < 4; t++) {
        const int cur = t & 1;
        if (t < 3) {
            const uint4* src = rep2 + (size_t)(cb * 4 + t + 1) * 1024;
#pragma unroll
            for (int j = 0; j < 4; j++)
                __builtin_amdgcn_global_load_lds(
                    (const GLOBAL_AS uint32_t*)(src + j * 256 + tid),
                    (LDS_AS uint32_t*)&lB[cur ^ 1][j * 256 + tid], 16, 0, 0);
        }

#pragma unroll
        for (int so = 0; so < 4; so++) {
            bf16x8 bF[4];
#pragma unroll
            for (int ks = 0; ks < 4; ks++)
                bF[ks] = *(const bf16x8*)&lB[cur][(ks * 4 + quad) * 64 + so * 16 + lcol];

            floatx4 acc[4];
            const floatx4 zf = {0.0f, 0.0f, 0.0f, 0.0f};
#pragma unroll
            for (int mi = 0; mi < 4; mi++) acc[mi] = zf;
#pragma unroll
            for (int ks = 0; ks < 4; ks++)
#pragma unroll
                for (int mi = 0; mi < 4; mi++)
                    acc[mi] = __builtin_amdgcn_mfma_f32_16x16x32_bf16(
                        aF[mi][ks], bF[ks], acc[mi], 0, 0, 0);

            const int c0s  = cb * 256 + t * 64 + so * 16;
            const int gcol = c0s + lcol;
            const bool diagS = ((c0s & ~63) == wbase);   // => rb==cb && t==w
            const bool partS = ((c0s & ~63) == pbase);   // => cb==rb+16 && t==w
            float cs = 0.0f;                             // colsum partial
            if (diagS | partS) {
#pragma unroll
                for (int mi = 0; mi < 4; mi++)
#pragma unroll
                    for (int r = 0; r < 4; r++) {
                        int grow = wbase + mi * 16 + quad * 4 + r;
                        float s = acc[mi][r];
                        if (partS && gcol == grow + 4096) {   // rb<16 here
                            float d = s * INV_K;              // raw dot
                            pos[grow] = d;
                            pos[grow + 4096] = d;
                        }
                        float e = __builtin_amdgcn_exp2f(s);
                        if (diagS && grow == gcol) e = 0.0f;  // mask j == i
                        rs[mi * 4 + r] += e;
                        cs += e;
                    }
            } else {
#pragma unroll
                for (int mi = 0; mi < 4; mi++)
#pragma unroll
                    for (int r = 0; r < 4; r++) {
                        float e = __builtin_amdgcn_exp2f(acc[mi][r]);
                        rs[mi * 4 + r] += e;
                        cs += e;
                    }
            }
            // colsum over the wave's 64 rows: reduce across quads
            cs += __shfl_xor(cs, 16, 64);
            cs += __shfl_xor(cs, 32, 64);
            if (quad == 0) colPart[w][t * 64 + so * 16 + lcol] = cs;
        }
        __syncthreads();   // drains prefetch, releases buffers, + colPart vis
    }

    // row partials: reduce rs across lane bits 0-3 (16 cols per quad)
#pragma unroll
    for (int s = 1; s < 16; s <<= 1)
#pragma unroll
        for (int k = 0; k < 16; k++) rs[k] += __shfl_xor(rs[k], s, 64);

    if (lcol == 0) {
#pragma unroll
        for (int k = 0; k < 16; k++) {
            int grow = wbase + (k >> 2) * 16 + quad * 4 + (k & 3);
            rowsumP[(size_t)grow * 32 + cb] = rs[k];   // slot cb
        }
    }

    // col partials -> mirror rows' slot rb (skip self-tile; loop-end barrier
    // already made colPart visible)
    if (rb != cb) {
        float c = colPart[0][tid] + colPart[1][tid] + colPart[2][tid] + colPart[3][tid];
        rowsumP[(size_t)(cb * 256 + tid) * 32 + rb] = c;
    }
}

// ---------------------------------------------------------------------------
// Kernel 3: loss = (1/8192) * sum_i [ log(sum_c rowsumP[i][c]) - 2*pos_i ]
// ---------------------------------------------------------------------------
__global__ __launch_bounds__(128) void fin_kernel(const float* __restrict__ rowsumP,
                                                  const float* __restrict__ pos,
                                                  float* __restrict__ out) {
    int row = blockIdx.x * 128 + threadIdx.x;
    const floatx4* rp = (const floatx4*)(rowsumP + (size_t)row * 32);
    float d = 0.0f;
#pragma unroll
    for (int j = 0; j < 8; j++) {
        floatx4 q = rp[j];
        d += (q[0] + q[1]) + (q[2] + q[3]);
    }
    float v = logf(d) - pos[row] * INV_T;
#pragma unroll
    for (int s = 1; s < 64; s <<= 1) v += __shfl_xor(v, s, 64);
    __shared__ float red[2];
    if ((threadIdx.x & 63) == 0) red[threadIdx.x >> 6] = v;
    __syncthreads();
    if (threadIdx.x == 0)
        atomicAdd(out, (red[0] + red[1]) * (1.0f / 8192.0f));
}

extern "C" void kernel_launch(void* const* d_in, const int* in_sizes, int n_in,
                              void* d_out, int out_size, void* d_ws, size_t ws_size,
                              hipStream_t stream) {
    const float* p1 = (const float*)d_in[0];
    const float* p2 = (const float*)d_in[1];
    float* out = (float*)d_out;

    char* ws       = (char*)d_ws;
    uint32_t* rep2 = (uint32_t*)ws;                             // 2 MB
    float* rowsumP = (float*)(ws + (2u << 20));                 // 1 MB
    float* pos     = (float*)(ws + (3u << 20));                 // 32 KB

    nrm_kernel<<<2048, 256, 0, stream>>>(p1, p2, rep2, out);
    sim_kernel<<<dim3(32, 32), 256, 0, stream>>>((const uint4*)rep2, rowsumP, pos);
    fin_kernel<<<64, 128, 0, stream>>>(rowsumP, pos, out);
}

// Round 8
// 98.500 us; speedup vs baseline: 1.4194x; 1.4194x over previous
//
#include <hip/hip_runtime.h>
#include <stdint.h>

typedef __bf16 bf16;
typedef bf16 bf16x8 __attribute__((ext_vector_type(8)));
typedef float floatx4 __attribute__((ext_vector_type(4)));

#define INV_T     2.0f                      // 1 / TEMPERATURE
#define SQRT_K    1.6986436206f             // sqrt(INV_T * log2(e))
#define INV_K     0.34657359028f            // ln(2)/2 = 1/(INV_T*log2(e))
#define GLOBAL_AS __attribute__((address_space(1)))
#define LDS_AS    __attribute__((address_space(3)))

// rep2 layout (16B chunks): chunk(r, ch) = (r>>6)*1024 + ch*64 + (r&63),
// ch = k>>3. MFMA A/B fragment loads and tile staging are fully coalesced,
// LDS fragment reads structurally conflict-free.

// ---------------------------------------------------------------------------
// Kernel 1: L2-normalize rows, scale by SQRT_K, write bf16 rep2 (swizzled).
// ---------------------------------------------------------------------------
__global__ __launch_bounds__(256) void nrm_kernel(const float* __restrict__ p1,
                                                  const float* __restrict__ p2,
                                                  uint32_t* __restrict__ rep2,
                                                  float* __restrict__ out) {
    int gt   = blockIdx.x * 256 + threadIdx.x;
    int row  = gt >> 6;
    int lane = gt & 63;
    const float* srcRow = (row < 4096) ? (p1 + (size_t)row * 128)
                                       : (p2 + (size_t)(row - 4096) * 128);
    float2 v = ((const float2*)srcRow)[lane];
    float ss = v.x * v.x + v.y * v.y;
#pragma unroll
    for (int s = 1; s < 64; s <<= 1) ss += __shfl_xor(ss, s, 64);
    float inv = SQRT_K / fmaxf(sqrtf(ss), 1e-12f);
    union { bf16 h[2]; uint32_t u; } pk;
    pk.h[0] = (bf16)(v.x * inv);
    pk.h[1] = (bf16)(v.y * inv);
    int chunk = (row >> 6) * 1024 + (lane >> 2) * 64 + (row & 63);
    rep2[chunk * 4 + (lane & 3)] = pk.u;
    if (gt == 0) *out = 0.0f;
}

// ---------------------------------------------------------------------------
// Kernel 2: SYMMETRIC rowsum partials + positive-pair dot.
// exp(sim) is symmetric -> compute only tiles (rb,cb) with cb >= rb (528 of
// 1024; lower-triangle blocks exit immediately). Each active block emits:
//   row partials (sum over its 256 cols)  -> rowsumP[row][cb]
//   col partials (sum over its 256 rows)  -> rowsumP[col][rb]   (cb != rb)
// Per-row slot coverage: {0..31} exactly once (cb>=b rowsums, rb<b colsums).
// Partner tiles (rb, rb+16) hold the (i, i+4096) pairs on their strip
// diagonals -> write pos[i] and pos[i+4096] from the same element.
// B staged via async global_load_lds, 2x16KB dbuf, 4 tiles, 1 barrier each.
// NOTE __launch_bounds__(256,3): (256,4) caps unified VGPR+AGPR at 128/wave
// -> aF[4][4] (64 VGPR) spills to scratch, 66 MB of spill traffic, 13x
// slowdown (R7: VGPR=64, WRITE_SIZE=68MB, 85us). 3 blocks/CU is the sweet
// spot: ~170-reg budget, no spill.
// ---------------------------------------------------------------------------
__global__ __launch_bounds__(256, 3) void sim_kernel(const uint4* __restrict__ rep2,
                                                     float* __restrict__ rowsumP,
                                                     float* __restrict__ pos) {
    __shared__ uint4 lB[2][1024];       // 32 KB
    __shared__ float colPart[4][256];   // 4 KB cross-wave colsum combine

    const int cb = blockIdx.x;     // col block: cols [cb*256, +256)
    const int rb = blockIdx.y;     // row block: rows [rb*256, +256)
    if (cb < rb) return;           // symmetry: upper triangle only

    const int tid  = threadIdx.x;
    const int w    = tid >> 6;
    const int lane = tid & 63;
    const int quad = lane >> 4;
    const int lcol = lane & 15;

    const int wbase = rb * 256 + w * 64;       // wave's rows (64-aligned)
    const int pbase = (wbase + 4096) & 8191;   // partner 64-col window

    // A fragments: rows wbase+mi*16+lcol, k = ks*32+quad*8..+7
    bf16x8 aF[4][4];
    const uint4* aG = rep2 + (size_t)(wbase >> 6) * 1024;
#pragma unroll
    for (int mi = 0; mi < 4; mi++)
#pragma unroll
        for (int ks = 0; ks < 4; ks++)
            aF[mi][ks] = *(const bf16x8*)&aG[(ks * 4 + quad) * 64 + mi * 16 + lcol];

    float rs[16];
#pragma unroll
    for (int i = 0; i < 16; i++) rs[i] = 0.0f;

    // stage tile 0 (cols cb*256..+63)
    {
        const uint4* src = rep2 + (size_t)(cb * 4) * 1024;
#pragma unroll
        for (int j = 0; j < 4; j++)
            __builtin_amdgcn_global_load_lds(
                (const GLOBAL_AS uint32_t*)(src + j * 256 + tid),
                (LDS_AS uint32_t*)&lB[0][j * 256 + tid], 16, 0, 0);
    }
    __syncthreads();

    for (int t = 0; t < 4; t++) {
        const int cur = t & 1;
        if (t < 3) {
            const uint4* src = rep2 + (size_t)(cb * 4 + t + 1) * 1024;
#pragma unroll
            for (int j = 0; j < 4; j++)
                __builtin_amdgcn_global_load_lds(
                    (const GLOBAL_AS uint32_t*)(src + j * 256 + tid),
                    (LDS_AS uint32_t*)&lB[cur ^ 1][j * 256 + tid], 16, 0, 0);
        }

#pragma unroll
        for (int so = 0; so < 4; so++) {
            bf16x8 bF[4];
#pragma unroll
            for (int ks = 0; ks < 4; ks++)
                bF[ks] = *(const bf16x8*)&lB[cur][(ks * 4 + quad) * 64 + so * 16 + lcol];

            floatx4 acc[4];
            const floatx4 zf = {0.0f, 0.0f, 0.0f, 0.0f};
#pragma unroll
            for (int mi = 0; mi < 4; mi++) acc[mi] = zf;
#pragma unroll
            for (int ks = 0; ks < 4; ks++)
#pragma unroll
                for (int mi = 0; mi < 4; mi++)
                    acc[mi] = __builtin_amdgcn_mfma_f32_16x16x32_bf16(
                        aF[mi][ks], bF[ks], acc[mi], 0, 0, 0);

            const int c0s  = cb * 256 + t * 64 + so * 16;
            const int gcol = c0s + lcol;
            const bool diagS = ((c0s & ~63) == wbase);   // => rb==cb && t==w
            const bool partS = ((c0s & ~63) == pbase);   // => cb==rb+16 && t==w
            float cs = 0.0f;                             // colsum partial
            if (diagS | partS) {
#pragma unroll
                for (int mi = 0; mi < 4; mi++)
#pragma unroll
                    for (int r = 0; r < 4; r++) {
                        int grow = wbase + mi * 16 + quad * 4 + r;
                        float s = acc[mi][r];
                        if (partS && gcol == grow + 4096) {   // rb<16 here
                            float d = s * INV_K;              // raw dot
                            pos[grow] = d;
                            pos[grow + 4096] = d;
                        }
                        float e = __builtin_amdgcn_exp2f(s);
                        if (diagS && grow == gcol) e = 0.0f;  // mask j == i
                        rs[mi * 4 + r] += e;
                        cs += e;
                    }
            } else {
#pragma unroll
                for (int mi = 0; mi < 4; mi++)
#pragma unroll
                    for (int r = 0; r < 4; r++) {
                        float e = __builtin_amdgcn_exp2f(acc[mi][r]);
                        rs[mi * 4 + r] += e;
                        cs += e;
                    }
            }
            // colsum over the wave's 64 rows: reduce across quads
            cs += __shfl_xor(cs, 16, 64);
            cs += __shfl_xor(cs, 32, 64);
            if (quad == 0) colPart[w][t * 64 + so * 16 + lcol] = cs;
        }
        __syncthreads();   // drains prefetch, releases buffers, + colPart vis
    }

    // row partials: reduce rs across lane bits 0-3 (16 cols per quad)
#pragma unroll
    for (int s = 1; s < 16; s <<= 1)
#pragma unroll
        for (int k = 0; k < 16; k++) rs[k] += __shfl_xor(rs[k], s, 64);

    if (lcol == 0) {
#pragma unroll
        for (int k = 0; k < 16; k++) {
            int grow = wbase + (k >> 2) * 16 + quad * 4 + (k & 3);
            rowsumP[(size_t)grow * 32 + cb] = rs[k];   // slot cb
        }
    }

    // col partials -> mirror rows' slot rb (skip self-tile; loop-end barrier
    // already made colPart visible)
    if (rb != cb) {
        float c = colPart[0][tid] + colPart[1][tid] + colPart[2][tid] + colPart[3][tid];
        rowsumP[(size_t)(cb * 256 + tid) * 32 + rb] = c;
    }
}

// ---------------------------------------------------------------------------
// Kernel 3: loss = (1/8192) * sum_i [ log(sum_c rowsumP[i][c]) - 2*pos_i ]
// ---------------------------------------------------------------------------
__global__ __launch_bounds__(128) void fin_kernel(const float* __restrict__ rowsumP,
                                                  const float* __restrict__ pos,
                                                  float* __restrict__ out) {
    int row = blockIdx.x * 128 + threadIdx.x;
    const floatx4* rp = (const floatx4*)(rowsumP + (size_t)row * 32);
    float d = 0.0f;
#pragma unroll
    for (int j = 0; j < 8; j++) {
        floatx4 q = rp[j];
        d += (q[0] + q[1]) + (q[2] + q[3]);
    }
    float v = logf(d) - pos[row] * INV_T;
#pragma unroll
    for (int s = 1; s < 64; s <<= 1) v += __shfl_xor(v, s, 64);
    __shared__ float red[2];
    if ((threadIdx.x & 63) == 0) red[threadIdx.x >> 6] = v;
    __syncthreads();
    if (threadIdx.x == 0)
        atomicAdd(out, (red[0] + red[1]) * (1.0f / 8192.0f));
}

extern "C" void kernel_launch(void* const* d_in, const int* in_sizes, int n_in,
                              void* d_out, int out_size, void* d_ws, size_t ws_size,
                              hipStream_t stream) {
    const float* p1 = (const float*)d_in[0];
    const float* p2 = (const float*)d_in[1];
    float* out = (float*)d_out;

    char* ws       = (char*)d_ws;
    uint32_t* rep2 = (uint32_t*)ws;                             // 2 MB
    float* rowsumP = (float*)(ws + (2u << 20));                 // 1 MB
    float* pos     = (float*)(ws + (3u << 20));                 // 32 KB

    nrm_kernel<<<2048, 256, 0, stream>>>(p1, p2, rep2, out);
    sim_kernel<<<dim3(32, 32), 256, 0, stream>>>((const uint4*)rep2, rowsumP, pos);
    fin_kernel<<<64, 128, 0, stream>>>(rowsumP, pos, out);
}

// Round 9
// 90.042 us; speedup vs baseline: 1.5527x; 1.0939x over previous
//
#include <hip/hip_runtime.h>
#include <stdint.h>

typedef __bf16 bf16;
typedef bf16 bf16x8 __attribute__((ext_vector_type(8)));
typedef float floatx4 __attribute__((ext_vector_type(4)));

#define INV_T     2.0f                      // 1 / TEMPERATURE
#define SQRT_K    1.6986436206f             // sqrt(INV_T * log2(e))
#define INV_K     0.34657359028f            // ln(2)/2 = 1/(INV_T*log2(e))
#define GLOBAL_AS __attribute__((address_space(1)))
#define LDS_AS    __attribute__((address_space(3)))

// rep2 layout (16B chunks): chunk(r, ch) = (r>>6)*1024 + ch*64 + (r&63),
// ch = k>>3. MFMA A/B fragment loads and tile staging are fully coalesced,
// LDS fragment reads structurally conflict-free.

// ---------------------------------------------------------------------------
// Kernel 1: L2-normalize rows, scale by SQRT_K, write bf16 rep2 (swizzled).
// ---------------------------------------------------------------------------
__global__ __launch_bounds__(256) void nrm_kernel(const float* __restrict__ p1,
                                                  const float* __restrict__ p2,
                                                  uint32_t* __restrict__ rep2,
                                                  float* __restrict__ out) {
    int gt   = blockIdx.x * 256 + threadIdx.x;
    int row  = gt >> 6;
    int lane = gt & 63;
    const float* srcRow = (row < 4096) ? (p1 + (size_t)row * 128)
                                       : (p2 + (size_t)(row - 4096) * 128);
    float2 v = ((const float2*)srcRow)[lane];
    float ss = v.x * v.x + v.y * v.y;
#pragma unroll
    for (int s = 1; s < 64; s <<= 1) ss += __shfl_xor(ss, s, 64);
    float inv = SQRT_K / fmaxf(sqrtf(ss), 1e-12f);
    union { bf16 h[2]; uint32_t u; } pk;
    pk.h[0] = (bf16)(v.x * inv);
    pk.h[1] = (bf16)(v.y * inv);
    int chunk = (row >> 6) * 1024 + (lane >> 2) * 64 + (row & 63);
    rep2[chunk * 4 + (lane & 3)] = pk.u;
    if (gt == 0) *out = 0.0f;
}

// ---------------------------------------------------------------------------
// Kernel 2: SYMMETRIC rowsum partials + positive-pair dot.
// exp(sim) is symmetric -> compute only tiles (rb,cb) with cb >= rb (528 of
// 1024; lower-triangle blocks exit immediately). Each active block emits:
//   row partials (sum over its 256 cols)  -> rowsumP[row][cb]
//   col partials (sum over its 256 rows)  -> rowsumP[col][rb]   (cb != rb)
// Partner tiles (rb, rb+16) write pos[i] and pos[i+4096] from the strip
// diagonal. B staged via async global_load_lds, 2x16KB dbuf, 4 barriers.
//
// REGISTER-BUDGET HISTORY (don't re-tighten):
//   (256,4): 128-reg cap -> aF spills, 66 MB scratch, 85 us  (R7)
//   (256,3): 170-reg cap -> still spills (VGPR=84, 36 MB, 43 us)  (R8) —
//            the colsum epilogue pushes the live set past what the
//            allocator fits once accum regs are reserved.
//   (256,2): 256-reg cap -> live set (~130) fits, no spill. Occupancy
//            2 blocks/CU is enough: work is VALU-exp bound ~3.2k cyc/wave.
// ---------------------------------------------------------------------------
__global__ __launch_bounds__(256, 2) void sim_kernel(const uint4* __restrict__ rep2,
                                                     float* __restrict__ rowsumP,
                                                     float* __restrict__ pos) {
    __shared__ uint4 lB[2][1024];       // 32 KB
    __shared__ float colPart[4][256];   // 4 KB cross-wave colsum combine

    const int cb = blockIdx.x;     // col block: cols [cb*256, +256)
    const int rb = blockIdx.y;     // row block: rows [rb*256, +256)
    if (cb < rb) return;           // symmetry: upper triangle only

    const int tid  = threadIdx.x;
    const int w    = tid >> 6;
    const int lane = tid & 63;
    const int quad = lane >> 4;
    const int lcol = lane & 15;

    const int wbase = rb * 256 + w * 64;       // wave's rows (64-aligned)
    const int pbase = (wbase + 4096) & 8191;   // partner 64-col window

    // A fragments: rows wbase+mi*16+lcol, k = ks*32+quad*8..+7
    bf16x8 aF[4][4];
    const uint4* aG = rep2 + (size_t)(wbase >> 6) * 1024;
#pragma unroll
    for (int mi = 0; mi < 4; mi++)
#pragma unroll
        for (int ks = 0; ks < 4; ks++)
            aF[mi][ks] = *(const bf16x8*)&aG[(ks * 4 + quad) * 64 + mi * 16 + lcol];

    float rs[16];
#pragma unroll
    for (int i = 0; i < 16; i++) rs[i] = 0.0f;

    // stage tile 0 (cols cb*256..+63)
    {
        const uint4* src = rep2 + (size_t)(cb * 4) * 1024;
#pragma unroll
        for (int j = 0; j < 4; j++)
            __builtin_amdgcn_global_load_lds(
                (const GLOBAL_AS uint32_t*)(src + j * 256 + tid),
                (LDS_AS uint32_t*)&lB[0][j * 256 + tid], 16, 0, 0);
    }
    __syncthreads();

    for (int t = 0; t < 4; t++) {
        const int cur = t & 1;
        if (t < 3) {
            const uint4* src = rep2 + (size_t)(cb * 4 + t + 1) * 1024;
#pragma unroll
            for (int j = 0; j < 4; j++)
                __builtin_amdgcn_global_load_lds(
                    (const GLOBAL_AS uint32_t*)(src + j * 256 + tid),
                    (LDS_AS uint32_t*)&lB[cur ^ 1][j * 256 + tid], 16, 0, 0);
        }

#pragma unroll
        for (int so = 0; so < 4; so++) {
            bf16x8 bF[4];
#pragma unroll
            for (int ks = 0; ks < 4; ks++)
                bF[ks] = *(const bf16x8*)&lB[cur][(ks * 4 + quad) * 64 + so * 16 + lcol];

            floatx4 acc[4];
            const floatx4 zf = {0.0f, 0.0f, 0.0f, 0.0f};
#pragma unroll
            for (int mi = 0; mi < 4; mi++) acc[mi] = zf;
#pragma unroll
            for (int ks = 0; ks < 4; ks++)
#pragma unroll
                for (int mi = 0; mi < 4; mi++)
                    acc[mi] = __builtin_amdgcn_mfma_f32_16x16x32_bf16(
                        aF[mi][ks], bF[ks], acc[mi], 0, 0, 0);

            const int c0s  = cb * 256 + t * 64 + so * 16;
            const int gcol = c0s + lcol;
            const bool diagS = ((c0s & ~63) == wbase);   // => rb==cb && t==w
            const bool partS = ((c0s & ~63) == pbase);   // => cb==rb+16 && t==w
            float cs = 0.0f;                             // colsum partial
            if (diagS | partS) {
#pragma unroll
                for (int mi = 0; mi < 4; mi++)
#pragma unroll
                    for (int r = 0; r < 4; r++) {
                        int grow = wbase + mi * 16 + quad * 4 + r;
                        float s = acc[mi][r];
                        if (partS && gcol == grow + 4096) {   // rb<16 here
                            float d = s * INV_K;              // raw dot
                            pos[grow] = d;
                            pos[grow + 4096] = d;
                        }
                        float e = __builtin_amdgcn_exp2f(s);
                        if (diagS && grow == gcol) e = 0.0f;  // mask j == i
                        rs[mi * 4 + r] += e;
                        cs += e;
                    }
            } else {
#pragma unroll
                for (int mi = 0; mi < 4; mi++)
#pragma unroll
                    for (int r = 0; r < 4; r++) {
                        float e = __builtin_amdgcn_exp2f(acc[mi][r]);
                        rs[mi * 4 + r] += e;
                        cs += e;
                    }
            }
            // colsum over the wave's 64 rows: reduce across quads
            cs += __shfl_xor(cs, 16, 64);
            cs += __shfl_xor(cs, 32, 64);
            if (quad == 0) colPart[w][t * 64 + so * 16 + lcol] = cs;
        }
        __syncthreads();   // drains prefetch, releases buffers, + colPart vis
    }

    // row partials: reduce rs across lane bits 0-3 (16 cols per quad)
#pragma unroll
    for (int s = 1; s < 16; s <<= 1)
#pragma unroll
        for (int k = 0; k < 16; k++) rs[k] += __shfl_xor(rs[k], s, 64);

    if (lcol == 0) {
#pragma unroll
        for (int k = 0; k < 16; k++) {
            int grow = wbase + (k >> 2) * 16 + quad * 4 + (k & 3);
            rowsumP[(size_t)grow * 32 + cb] = rs[k];   // slot cb
        }
    }

    // col partials -> mirror rows' slot rb (skip self-tile; loop-end barrier
    // already made colPart visible)
    if (rb != cb) {
        float c = colPart[0][tid] + colPart[1][tid] + colPart[2][tid] + colPart[3][tid];
        rowsumP[(size_t)(cb * 256 + tid) * 32 + rb] = c;
    }
}

// ---------------------------------------------------------------------------
// Kernel 3: loss = (1/8192) * sum_i [ log(sum_c rowsumP[i][c]) - 2*pos_i ]
// ---------------------------------------------------------------------------
__global__ __launch_bounds__(128) void fin_kernel(const float* __restrict__ rowsumP,
                                                  const float* __restrict__ pos,
                                                  float* __restrict__ out) {
    int row = blockIdx.x * 128 + threadIdx.x;
    const floatx4* rp = (const floatx4*)(rowsumP + (size_t)row * 32);
    float d = 0.0f;
#pragma unroll
    for (int j = 0; j < 8; j++) {
        floatx4 q = rp[j];
        d += (q[0] + q[1]) + (q[2] + q[3]);
    }
    float v = logf(d) - pos[row] * INV_T;
#pragma unroll
    for (int s = 1; s < 64; s <<= 1) v += __shfl_xor(v, s, 64);
    __shared__ float red[2];
    if ((threadIdx.x & 63) == 0) red[threadIdx.x >> 6] = v;
    __syncthreads();
    if (threadIdx.x == 0)
        atomicAdd(out, (red[0] + red[1]) * (1.0f / 8192.0f));
}

extern "C" void kernel_launch(void* const* d_in, const int* in_sizes, int n_in,
                              void* d_out, int out_size, void* d_ws, size_t ws_size,
                              hipStream_t stream) {
    const float* p1 = (const float*)d_in[0];
    const float* p2 = (const float*)d_in[1];
    float* out = (float*)d_out;

    char* ws       = (char*)d_ws;
    uint32_t* rep2 = (uint32_t*)ws;                             // 2 MB
    float* rowsumP = (float*)(ws + (2u << 20));                 // 1 MB
    float* pos     = (float*)(ws + (3u << 20));                 // 32 KB

    nrm_kernel<<<2048, 256, 0, stream>>>(p1, p2, rep2, out);
    sim_kernel<<<dim3(32, 32), 256, 0, stream>>>((const uint4*)rep2, rowsumP, pos);
    fin_kernel<<<64, 128, 0, stream>>>(rowsumP, pos, out);
}